// Round 6
// baseline (4142.958 us; speedup 1.0000x reference)
//
#include <hip/hip_runtime.h>
#include <hip/hip_bf16.h>

#define N_USERS 100000
#define E_HYPER 50000
#define NNZ_E   800000
#define T_STEPS 8
#define DIM     64
#define IDXM    0xFFFFF

typedef __bf16 bf16x8 __attribute__((ext_vector_type(8)));
typedef float  f32x4  __attribute__((ext_vector_type(4)));

// ---------------------------------------------------------------------------
// dtype-adaptive load: flag==1 -> buffer is fp32, flag==0 -> buffer is bf16
// ---------------------------------------------------------------------------
__device__ __forceinline__ float ld_in(const void* p, size_t i, int f32)
{
    return f32 ? ((const float*)p)[i]
               : __bfloat162float(((const __hip_bfloat16*)p)[i]);
}

// ---------------------------------------------------------------------------
// Kernel 0: detect input dtype (bf16 N(0,1/8) halfwords have exponent<=126;
// fp32 low-halfword garbage trips e>126 ~50% of the time).
// ---------------------------------------------------------------------------
__global__ void k_detect(const unsigned short* __restrict__ raw, int* __restrict__ flag)
{
    __shared__ int cnt;
    if (threadIdx.x == 0) cnt = 0;
    __syncthreads();
    int c = 0;
    for (int i = threadIdx.x; i < 4096; i += blockDim.x) {
        int e = (raw[i] >> 7) & 0xFF;
        if (e > 126) c++;
    }
    atomicAdd(&cnt, c);
    __syncthreads();
    if (threadIdx.x == 0) *flag = (cnt > 64) ? 1 : 0;
}

// ---------------------------------------------------------------------------
// Kernel 0b: convert small params to fp32 staging.
// st: W[0,4096) b[4096,4160) w1[4160,8256) b1[8256,8320) w2[8320,8384) b2[8384]
// ---------------------------------------------------------------------------
__global__ void k_convert_params(
    const void* W, const void* b, const void* w1, const void* b1,
    const void* w2, const void* b2, const int* __restrict__ flag,
    float* __restrict__ st)
{
    int f = *flag;
    int i = blockIdx.x * blockDim.x + threadIdx.x;
    if (i < 4096)          st[i] = ld_in(W,  i,        f);
    else if (i < 4160)     st[i] = ld_in(b,  i - 4096, f);
    else if (i < 8256)     st[i] = ld_in(w1, i - 4160, f);
    else if (i < 8320)     st[i] = ld_in(b1, i - 8256, f);
    else if (i < 8384)     st[i] = ld_in(w2, i - 8320, f);
    else if (i == 8384)    st[i] = ld_in(b2, 0,        f);
}

// ---------------------------------------------------------------------------
// Kernel 1: h = relu(user_emb @ W_conv + b_conv) -> bf16 [N, D]
// ---------------------------------------------------------------------------
__global__ __launch_bounds__(256) void k_transform(
    const void* __restrict__ emb, const int* __restrict__ flag,
    const float* __restrict__ st, __hip_bfloat16* __restrict__ h)
{
    __shared__ float Wl[DIM * DIM];
    __shared__ float bl[DIM];
    for (int i = threadIdx.x; i < DIM * DIM; i += blockDim.x) Wl[i] = st[i];
    if (threadIdx.x < DIM) bl[threadIdx.x] = st[4096 + threadIdx.x];
    __syncthreads();

    int f = *flag;
    int wave = threadIdx.x >> 6, lane = threadIdx.x & 63;
    int wavesTotal = gridDim.x * (blockDim.x >> 6);
    for (int row = blockIdx.x * (blockDim.x >> 6) + wave; row < N_USERS;
         row += wavesTotal) {
        size_t base = (size_t)row * DIM;
        float v = ld_in(emb, base + lane, f);
        float acc = bl[lane];
#pragma unroll
        for (int k = 0; k < DIM; ++k)
            acc += __shfl(v, k, 64) * Wl[k * DIM + lane];
        h[base + lane] = __float2bfloat16(fmaxf(acc, 0.f));
    }
}

// ---------------------------------------------------------------------------
// Kernel 2: build tagged linked lists. head value = (tag<<20)|i, tag=t+1.
// Stale/poison/zero heads decode as empty -> no per-step memset needed.
// ---------------------------------------------------------------------------
__global__ __launch_bounds__(256) void k_build(
    const int* __restrict__ nodes, const int* __restrict__ hyper,
    int* __restrict__ head_e, int* __restrict__ next_e,
    int* __restrict__ head_n, int* __restrict__ next_n, int tag)
{
    int i = blockIdx.x * blockDim.x + threadIdx.x;
    if (i >= NNZ_E) return;
    int tv = (tag << 20) | i;
    next_e[i] = atomicExch(&head_e[hyper[i]], tv);
    next_n[i] = atomicExch(&head_n[nodes[i]], tv);
}

__device__ __forceinline__ int dec(int v, int tag)
{
    return ((v >> 20) == tag) ? (v & IDXM) : -1;
}

// ---------------------------------------------------------------------------
// Kernel 3: gather h rows per hyperedge, average -> e (bf16)
// one wave walks 8 chains concurrently
// ---------------------------------------------------------------------------
__global__ __launch_bounds__(256) void k_gather_e(
    const __hip_bfloat16* __restrict__ h,
    const int* __restrict__ nodes,
    const int* __restrict__ head_e, const int* __restrict__ next_e,
    __hip_bfloat16* __restrict__ e, int tag)
{
    int lane = threadIdx.x & 63;
    int wid = blockIdx.x * (blockDim.x >> 6) + (threadIdx.x >> 6);
    int nW  = gridDim.x * (blockDim.x >> 6);
    for (int s0 = wid * 8; s0 < E_HYPER; s0 += nW * 8) {
        int idx[8]; float acc[8]; int cnt[8];
#pragma unroll
        for (int c = 0; c < 8; ++c) {
            int sg = s0 + c;
            idx[c] = (sg < E_HYPER) ? dec(head_e[sg], tag) : -1;
            acc[c] = 0.f; cnt[c] = 0;
        }
        while (true) {
            bool any = false;
#pragma unroll
            for (int c = 0; c < 8; ++c) any = any || (idx[c] >= 0);
            if (!any) break;
            int nxt[8], nd[8];
#pragma unroll
            for (int c = 0; c < 8; ++c)
                if (idx[c] >= 0) { nxt[c] = next_e[idx[c]]; nd[c] = nodes[idx[c]]; }
#pragma unroll
            for (int c = 0; c < 8; ++c)
                if (idx[c] >= 0) {
                    acc[c] += __bfloat162float(h[(size_t)nd[c] * DIM + lane]);
                    cnt[c]++; idx[c] = dec(nxt[c], tag);
                }
        }
#pragma unroll
        for (int c = 0; c < 8; ++c) {
            int sg = s0 + c;
            if (sg < E_HYPER)
                e[(size_t)sg * DIM + lane] =
                    __float2bfloat16(acc[c] / (float)max(cnt[c], 1));
        }
    }
}

// ---------------------------------------------------------------------------
// carry access (3 modes): f32-in-dout | f32-in-ws | bf16-in-dout
// ---------------------------------------------------------------------------
__device__ __forceinline__ float ld_carry(void* out, float* cws, size_t i,
                                          int f, int use_ws)
{
    if (f) return ((float*)out)[i];
    if (use_ws) return cws[i];
    return __bfloat162float(((__hip_bfloat16*)out)[i]);
}
__device__ __forceinline__ void st_carry(void* out, float* cws, size_t i,
                                         int f, int use_ws, int wr, float v)
{
    if (f) { ((float*)out)[i] = v; return; }
    if (use_ws) {
        cws[i] = v;
        if (wr) ((__hip_bfloat16*)out)[i] = __float2bfloat16(v);
        return;
    }
    ((__hip_bfloat16*)out)[i] = __float2bfloat16(v);
}

// ---------------------------------------------------------------------------
// Kernel 4 (merged): per 16-row tile: walk 16 node-chains (dy), load carry,
// MFMA score, softmax, blend, store carry. t==0 (do_fuse=0): store dy only.
// LDS transpose (stride 65) moves lane=dim data into MFMA A-fragments.
// ---------------------------------------------------------------------------
__global__ __launch_bounds__(256) void k_gather_fuse(
    const __hip_bfloat16* __restrict__ e_buf,
    const int* __restrict__ hyper,
    const int* __restrict__ head_n, const int* __restrict__ next_n,
    void* __restrict__ dout, float* __restrict__ cws,
    const float* __restrict__ st, const int* __restrict__ flag,
    int use_ws, int tag, int do_fuse, int write_out)
{
    __shared__ float lt[4][2][16 * 65];
    int f = *flag;
    int lane = threadIdx.x & 63;
    int wavein = threadIdx.x >> 6;
    int quad = lane >> 4, m = lane & 15;

    // persistent B-fragments of w1 + b1/w2 slices (verified layout from R5)
    bf16x8 bw[4][2];
    float b1v[4], w2v[4];
#pragma unroll
    for (int nt = 0; nt < 4; ++nt) {
#pragma unroll
        for (int kb = 0; kb < 2; ++kb)
#pragma unroll
            for (int j = 0; j < 8; ++j) {
                int k = kb * 32 + quad * 8 + j;
                bw[nt][kb][j] = (__bf16)st[4160 + k * 64 + nt * 16 + m];
            }
        b1v[nt] = st[8256 + nt * 16 + m];
        w2v[nt] = st[8320 + nt * 16 + m];
    }

    int wid = blockIdx.x * 4 + wavein;
    int nW  = gridDim.x * 4;
    const int NT = N_USERS / 16;
    float* Lh = lt[wavein][0];
    float* Ld = lt[wavein][1];

    for (int tile = wid; tile < NT; tile += nW) {
        int s0 = tile * 16;

        // ---- 16-chain walk (lane = dim) ----
        int idx[16]; float acc[16]; int cnt[16];
#pragma unroll
        for (int c = 0; c < 16; ++c) {
            idx[c] = dec(head_n[s0 + c], tag);
            acc[c] = 0.f; cnt[c] = 0;
        }
        while (true) {
            bool any = false;
#pragma unroll
            for (int c = 0; c < 16; ++c) any = any || (idx[c] >= 0);
            if (!any) break;
            int nxt[16], hy[16];
#pragma unroll
            for (int c = 0; c < 16; ++c)
                if (idx[c] >= 0) { nxt[c] = next_n[idx[c]]; hy[c] = hyper[idx[c]]; }
#pragma unroll
            for (int c = 0; c < 16; ++c)
                if (idx[c] >= 0) {
                    acc[c] += __bfloat162float(e_buf[(size_t)hy[c] * DIM + lane]);
                    cnt[c]++; idx[c] = dec(nxt[c], tag);
                }
        }
        float dy[16];
#pragma unroll
        for (int c = 0; c < 16; ++c) dy[c] = acc[c] / (float)max(cnt[c], 1);

        if (!do_fuse) {
#pragma unroll
            for (int c = 0; c < 16; ++c)
                st_carry(dout, cws, (size_t)(s0 + c) * DIM + lane, f, use_ws,
                         0, dy[c]);
            continue;
        }

        float hid[16];
#pragma unroll
        for (int c = 0; c < 16; ++c)
            hid[c] = ld_carry(dout, cws, (size_t)(s0 + c) * DIM + lane, f, use_ws);

        // ---- LDS transpose: lane=dim -> A-fragments ----
#pragma unroll
        for (int c = 0; c < 16; ++c) {
            Lh[c * 65 + lane] = hid[c];
            Ld[c * 65 + lane] = dy[c];
        }
        __asm__ volatile("s_waitcnt lgkmcnt(0)" ::: "memory");

        bf16x8 ah[2], ad[2];
#pragma unroll
        for (int kb = 0; kb < 2; ++kb)
#pragma unroll
            for (int j = 0; j < 8; ++j) {
                ah[kb][j] = (__bf16)Lh[m * 65 + kb * 32 + quad * 8 + j];
                ad[kb][j] = (__bf16)Ld[m * 65 + kb * 32 + quad * 8 + j];
            }

        // ---- score matmul + tanh + w2 ----
        float zh[4] = {0.f, 0.f, 0.f, 0.f};
        float zd[4] = {0.f, 0.f, 0.f, 0.f};
#pragma unroll
        for (int nt = 0; nt < 4; ++nt) {
            f32x4 acch = {0.f, 0.f, 0.f, 0.f};
            f32x4 accd = {0.f, 0.f, 0.f, 0.f};
#pragma unroll
            for (int kb = 0; kb < 2; ++kb) {
                acch = __builtin_amdgcn_mfma_f32_16x16x32_bf16(ah[kb], bw[nt][kb], acch, 0, 0, 0);
                accd = __builtin_amdgcn_mfma_f32_16x16x32_bf16(ad[kb], bw[nt][kb], accd, 0, 0, 0);
            }
#pragma unroll
            for (int reg = 0; reg < 4; ++reg) {
                zh[reg] += tanhf(acch[reg] + b1v[nt]) * w2v[nt];
                zd[reg] += tanhf(accd[reg] + b1v[nt]) * w2v[nt];
            }
        }
        // reduce over 16 cols within quad; row = quad*4+reg
        float s[4];
#pragma unroll
        for (int reg = 0; reg < 4; ++reg) {
#pragma unroll
            for (int off = 1; off < 16; off <<= 1) {
                zh[reg] += __shfl_xor(zh[reg], off, 64);
                zd[reg] += __shfl_xor(zd[reg], off, 64);
            }
            float mm = fmaxf(zh[reg], zd[reg]);
            float eh = expf(zh[reg] - mm), ed = expf(zd[reg] - mm);
            s[reg] = eh / (eh + ed);
        }
        // broadcast per-row s to all lanes: row c = (c>>2)*4 + (c&3)
        float sc[16];
#pragma unroll
        for (int c = 0; c < 16; ++c)
            sc[c] = __shfl(s[c & 3], (c >> 2) * 16, 64);

        // ---- blend + coalesced store ----
#pragma unroll
        for (int c = 0; c < 16; ++c) {
            float v = sc[c] * hid[c] + (1.f - sc[c]) * dy[c];
            st_carry(dout, cws, (size_t)(s0 + c) * DIM + lane, f, use_ws,
                     write_out, v);
        }
    }
}

// ---------------------------------------------------------------------------
extern "C" void kernel_launch(void* const* d_in, const int* in_sizes, int n_in,
                              void* d_out, int out_size, void* d_ws,
                              size_t ws_size, hipStream_t stream)
{
    const void* user_emb = d_in[0];
    const void* W_conv   = d_in[1];
    const void* b_conv   = d_in[2];
    const void* fus_w1   = d_in[3];
    const void* fus_b1   = d_in[4];
    const void* fus_w2   = d_in[5];
    const void* fus_b2   = d_in[6];
    const int* edge_nodes = (const int*)d_in[7];
    const int* edge_hyper = (const int*)d_in[8];

    const size_t ND = (size_t)N_USERS * DIM;   // 6,400,000

    // ws layout (fp32 word offsets) — identical to proven base (51.83 MB):
    //   0        : flag
    //   16       : st fp32 [8448]
    //   8464     : head_e int [50000]
    //   58464    : head_n int [100000]
    //   158464   : next_e int [800000]
    //   958464   : next_n int [800000]
    //   1758464  : e bf16 [ED]
    //   3358464  : (unused, former dy)
    //   9758464  : h bf16 [ND]
    //   12958464 : optional fp32 carry [ND]  -> 77.43 MB
    float* ws = (float*)d_ws;
    int*   flag   = (int*)ws;
    float* st     = ws + 16;
    int*   head_e = (int*)(ws + 8464);
    int*   head_n = (int*)(ws + 58464);
    int*   next_e = (int*)(ws + 158464);
    int*   next_n = (int*)(ws + 958464);
    __hip_bfloat16* e_buf = (__hip_bfloat16*)(ws + 1758464);
    __hip_bfloat16* h = (__hip_bfloat16*)(ws + 9758464);
    float* carry_ws   = ws + 12958464;

    const size_t need_ws_carry = (12958464 + ND) * 4;
    const int use_ws = (ws_size >= need_ws_carry) ? 1 : 0;

    k_detect<<<1, 256, 0, stream>>>((const unsigned short*)user_emb, flag);
    k_convert_params<<<(8385 + 255) / 256, 256, 0, stream>>>(
        W_conv, b_conv, fus_w1, fus_b1, fus_w2, fus_b2, flag, st);
    k_transform<<<1024, 256, 0, stream>>>(user_emb, flag, st, h);

    for (int t = 0; t < T_STEPS; ++t) {
        const int* nodes = edge_nodes + (size_t)t * NNZ_E;
        const int* hyper = edge_hyper + (size_t)t * NNZ_E;
        int tag = t + 1;

        k_build<<<(NNZ_E + 255) / 256, 256, 0, stream>>>(
            nodes, hyper, head_e, next_e, head_n, next_n, tag);
        // E/8 chains per wave: 6250 waves -> 1563 blocks
        k_gather_e<<<1563, 256, 0, stream>>>(h, nodes, head_e, next_e, e_buf, tag);
        // 6250 tiles of 16 rows
        k_gather_fuse<<<1024, 256, 0, stream>>>(
            e_buf, hyper, head_n, next_n, d_out, carry_ws, st, flag,
            use_ws, tag, (t > 0) ? 1 : 0, (t == T_STEPS - 1) ? 1 : 0);
    }
}

// Round 7
// 1996.224 us; speedup vs baseline: 2.0754x; 2.0754x over previous
//
#include <hip/hip_runtime.h>
#include <hip/hip_bf16.h>

#define N_USERS 100000
#define E_HYPER 50000
#define NNZ_E   800000
#define T_STEPS 8
#define DIM     64
#define IDXM    0xFFFFF

typedef __bf16 bf16x8 __attribute__((ext_vector_type(8)));
typedef float  f32x4  __attribute__((ext_vector_type(4)));

// ---------------------------------------------------------------------------
// dtype-adaptive load: flag==1 -> buffer is fp32, flag==0 -> buffer is bf16
// ---------------------------------------------------------------------------
__device__ __forceinline__ float ld_in(const void* p, size_t i, int f32)
{
    return f32 ? ((const float*)p)[i]
               : __bfloat162float(((const __hip_bfloat16*)p)[i]);
}

// ---------------------------------------------------------------------------
// Kernel 0: detect input dtype (bf16 N(0,1/8) halfwords have exponent<=126;
// fp32 low-halfword garbage trips e>126 ~50% of the time).
// ---------------------------------------------------------------------------
__global__ void k_detect(const unsigned short* __restrict__ raw, int* __restrict__ flag)
{
    __shared__ int cnt;
    if (threadIdx.x == 0) cnt = 0;
    __syncthreads();
    int c = 0;
    for (int i = threadIdx.x; i < 4096; i += blockDim.x) {
        int e = (raw[i] >> 7) & 0xFF;
        if (e > 126) c++;
    }
    atomicAdd(&cnt, c);
    __syncthreads();
    if (threadIdx.x == 0) *flag = (cnt > 64) ? 1 : 0;
}

// ---------------------------------------------------------------------------
// Kernel 0b: convert small params to fp32 staging.
// st: W[0,4096) b[4096,4160) w1[4160,8256) b1[8256,8320) w2[8320,8384) b2[8384]
// ---------------------------------------------------------------------------
__global__ void k_convert_params(
    const void* W, const void* b, const void* w1, const void* b1,
    const void* w2, const void* b2, const int* __restrict__ flag,
    float* __restrict__ st)
{
    int f = *flag;
    int i = blockIdx.x * blockDim.x + threadIdx.x;
    if (i < 4096)          st[i] = ld_in(W,  i,        f);
    else if (i < 4160)     st[i] = ld_in(b,  i - 4096, f);
    else if (i < 8256)     st[i] = ld_in(w1, i - 4160, f);
    else if (i < 8320)     st[i] = ld_in(b1, i - 8256, f);
    else if (i < 8384)     st[i] = ld_in(w2, i - 8320, f);
    else if (i == 8384)    st[i] = ld_in(b2, 0,        f);
}

// ---------------------------------------------------------------------------
// Kernel 1: h = relu(user_emb @ W_conv + b_conv) -> bf16 [N, D]
// ---------------------------------------------------------------------------
__global__ __launch_bounds__(256) void k_transform(
    const void* __restrict__ emb, const int* __restrict__ flag,
    const float* __restrict__ st, __hip_bfloat16* __restrict__ h)
{
    __shared__ float Wl[DIM * DIM];
    __shared__ float bl[DIM];
    for (int i = threadIdx.x; i < DIM * DIM; i += blockDim.x) Wl[i] = st[i];
    if (threadIdx.x < DIM) bl[threadIdx.x] = st[4096 + threadIdx.x];
    __syncthreads();

    int f = *flag;
    int wave = threadIdx.x >> 6, lane = threadIdx.x & 63;
    int wavesTotal = gridDim.x * (blockDim.x >> 6);
    for (int row = blockIdx.x * (blockDim.x >> 6) + wave; row < N_USERS;
         row += wavesTotal) {
        size_t base = (size_t)row * DIM;
        float v = ld_in(emb, base + lane, f);
        float acc = bl[lane];
#pragma unroll
        for (int k = 0; k < DIM; ++k)
            acc += __shfl(v, k, 64) * Wl[k * DIM + lane];
        h[base + lane] = __float2bfloat16(fmaxf(acc, 0.f));
    }
}

// ---------------------------------------------------------------------------
// Kernel 2: build tagged linked lists. head value = (tag<<20)|i, tag=t+1.
// Stale/poison heads decode as empty -> no memset needed (ws re-poisoned
// 0xAA before every timed launch; 0xAAA tag never matches 1..8).
// ---------------------------------------------------------------------------
__global__ __launch_bounds__(256) void k_build(
    const int* __restrict__ nodes, const int* __restrict__ hyper,
    int* __restrict__ head_e, int* __restrict__ next_e,
    int* __restrict__ head_n, int* __restrict__ next_n, int tag)
{
    int i = blockIdx.x * blockDim.x + threadIdx.x;
    if (i >= NNZ_E) return;
    int tv = (tag << 20) | i;
    next_e[i] = atomicExch(&head_e[hyper[i]], tv);
    next_n[i] = atomicExch(&head_n[nodes[i]], tv);
}

__device__ __forceinline__ int dec(int v, int tag)
{
    return ((v >> 20) == tag) ? (v & IDXM) : -1;
}

// ---------------------------------------------------------------------------
// Kernel 3: gather h rows per hyperedge, average -> e (bf16)
// one wave walks 8 chains concurrently (lean state, high occupancy)
// ---------------------------------------------------------------------------
__global__ __launch_bounds__(256) void k_gather_e(
    const __hip_bfloat16* __restrict__ h,
    const int* __restrict__ nodes,
    const int* __restrict__ head_e, const int* __restrict__ next_e,
    __hip_bfloat16* __restrict__ e, int tag)
{
    int lane = threadIdx.x & 63;
    int wid = blockIdx.x * (blockDim.x >> 6) + (threadIdx.x >> 6);
    int nW  = gridDim.x * (blockDim.x >> 6);
    for (int s0 = wid * 8; s0 < E_HYPER; s0 += nW * 8) {
        int idx[8]; float acc[8]; int cnt[8];
#pragma unroll
        for (int c = 0; c < 8; ++c) {
            int sg = s0 + c;
            idx[c] = (sg < E_HYPER) ? dec(head_e[sg], tag) : -1;
            acc[c] = 0.f; cnt[c] = 0;
        }
        while (true) {
            bool any = false;
#pragma unroll
            for (int c = 0; c < 8; ++c) any = any || (idx[c] >= 0);
            if (!any) break;
            int nxt[8], nd[8];
#pragma unroll
            for (int c = 0; c < 8; ++c)
                if (idx[c] >= 0) { nxt[c] = next_e[idx[c]]; nd[c] = nodes[idx[c]]; }
#pragma unroll
            for (int c = 0; c < 8; ++c)
                if (idx[c] >= 0) {
                    acc[c] += __bfloat162float(h[(size_t)nd[c] * DIM + lane]);
                    cnt[c]++; idx[c] = dec(nxt[c], tag);
                }
        }
#pragma unroll
        for (int c = 0; c < 8; ++c) {
            int sg = s0 + c;
            if (sg < E_HYPER)
                e[(size_t)sg * DIM + lane] =
                    __float2bfloat16(acc[c] / (float)max(cnt[c], 1));
        }
    }
}

// ---------------------------------------------------------------------------
// carry access (3 modes): f32-in-dout | f32-in-ws | bf16-in-dout
// ---------------------------------------------------------------------------
__device__ __forceinline__ float ld_carry(void* out, float* cws, size_t i,
                                          int f, int use_ws)
{
    if (f) return ((float*)out)[i];
    if (use_ws) return cws[i];
    return __bfloat162float(((__hip_bfloat16*)out)[i]);
}
__device__ __forceinline__ void st_carry(void* out, float* cws, size_t i,
                                         int f, int use_ws, int wr, float v)
{
    if (f) { ((float*)out)[i] = v; return; }
    if (use_ws) {
        cws[i] = v;
        if (wr) ((__hip_bfloat16*)out)[i] = __float2bfloat16(v);
        return;
    }
    ((__hip_bfloat16*)out)[i] = __float2bfloat16(v);
}

// ---------------------------------------------------------------------------
// Kernel 4: gather e rows per node, average -> dy (fp32) or carry (t==0)
// 8 chains per wave
// ---------------------------------------------------------------------------
__global__ __launch_bounds__(256) void k_gather_n(
    const __hip_bfloat16* __restrict__ e,
    const int* __restrict__ hyper,
    const int* __restrict__ head_n, const int* __restrict__ next_n,
    float* __restrict__ dy,
    void* __restrict__ out, float* __restrict__ cws,
    const int* __restrict__ flag, int use_ws, int to_carry, int tag)
{
    int f = *flag;
    int lane = threadIdx.x & 63;
    int wid = blockIdx.x * (blockDim.x >> 6) + (threadIdx.x >> 6);
    int nW  = gridDim.x * (blockDim.x >> 6);
    for (int s0 = wid * 8; s0 < N_USERS; s0 += nW * 8) {
        int idx[8]; float acc[8]; int cnt[8];
#pragma unroll
        for (int c = 0; c < 8; ++c) {
            int sg = s0 + c;
            idx[c] = (sg < N_USERS) ? dec(head_n[sg], tag) : -1;
            acc[c] = 0.f; cnt[c] = 0;
        }
        while (true) {
            bool any = false;
#pragma unroll
            for (int c = 0; c < 8; ++c) any = any || (idx[c] >= 0);
            if (!any) break;
            int nxt[8], hy[8];
#pragma unroll
            for (int c = 0; c < 8; ++c)
                if (idx[c] >= 0) { nxt[c] = next_n[idx[c]]; hy[c] = hyper[idx[c]]; }
#pragma unroll
            for (int c = 0; c < 8; ++c)
                if (idx[c] >= 0) {
                    acc[c] += __bfloat162float(e[(size_t)hy[c] * DIM + lane]);
                    cnt[c]++; idx[c] = dec(nxt[c], tag);
                }
        }
#pragma unroll
        for (int c = 0; c < 8; ++c) {
            int sg = s0 + c;
            if (sg < N_USERS) {
                float v = acc[c] / (float)max(cnt[c], 1);
                size_t o = (size_t)sg * DIM + lane;
                if (to_carry) st_carry(out, cws, o, f, use_ws, 0, v);
                else          dy[o] = v;
            }
        }
    }
}

// ---------------------------------------------------------------------------
// Kernel 5 (t>=1): carry = fuse(carry, dy) via MFMA 16x16x32 bf16.
// One wave per 16-row tile (proven R5 version). b2 cancels in 2-way softmax.
// ---------------------------------------------------------------------------
__global__ __launch_bounds__(256) void k_fuse_mfma(
    void* __restrict__ dout, float* __restrict__ cws,
    const float* __restrict__ dy_buf,
    const float* __restrict__ st, const int* __restrict__ flag,
    int use_ws, int write_out)
{
    int f = *flag;
    float* cf = f ? (float*)dout : (use_ws ? cws : (float*)0);
    __hip_bfloat16* cb = (__hip_bfloat16*)dout;

    int lane = threadIdx.x & 63;
    int quad = lane >> 4;
    int m    = lane & 15;

    bf16x8 bw[4][2];
    float b1v[4], w2v[4];
#pragma unroll
    for (int nt = 0; nt < 4; ++nt) {
#pragma unroll
        for (int kb = 0; kb < 2; ++kb)
#pragma unroll
            for (int j = 0; j < 8; ++j) {
                int k = kb * 32 + quad * 8 + j;
                bw[nt][kb][j] = (__bf16)st[4160 + k * 64 + nt * 16 + m];
            }
        b1v[nt] = st[8256 + nt * 16 + m];
        w2v[nt] = st[8320 + nt * 16 + m];
    }

    int wid = blockIdx.x * (blockDim.x >> 6) + (threadIdx.x >> 6);
    int nW  = gridDim.x * (blockDim.x >> 6);
    const int NT = N_USERS / 16;

    for (int tile = wid; tile < NT; tile += nW) {
        int row = tile * 16 + m;
        size_t base = (size_t)row * DIM;

        float hidf[2][8], dyf[2][8];
        if (cf) {
            const f32x4* cp = (const f32x4*)(cf + base);
            const f32x4* dp = (const f32x4*)(dy_buf + base);
#pragma unroll
            for (int kb = 0; kb < 2; ++kb) {
                f32x4 a = cp[kb * 8 + quad * 2], b = cp[kb * 8 + quad * 2 + 1];
                f32x4 c = dp[kb * 8 + quad * 2], d = dp[kb * 8 + quad * 2 + 1];
#pragma unroll
                for (int j = 0; j < 4; ++j) {
                    hidf[kb][j] = a[j]; hidf[kb][4 + j] = b[j];
                    dyf[kb][j]  = c[j]; dyf[kb][4 + j]  = d[j];
                }
            }
        } else {
#pragma unroll
            for (int kb = 0; kb < 2; ++kb)
#pragma unroll
                for (int j = 0; j < 8; ++j) {
                    int k = kb * 32 + quad * 8 + j;
                    hidf[kb][j] = __bfloat162float(cb[base + k]);
                    dyf[kb][j]  = dy_buf[base + k];
                }
        }

        bf16x8 ah[2], ad[2];
#pragma unroll
        for (int kb = 0; kb < 2; ++kb)
#pragma unroll
            for (int j = 0; j < 8; ++j) {
                ah[kb][j] = (__bf16)hidf[kb][j];
                ad[kb][j] = (__bf16)dyf[kb][j];
            }

        float zh[4] = {0.f, 0.f, 0.f, 0.f};
        float zd[4] = {0.f, 0.f, 0.f, 0.f};
#pragma unroll
        for (int nt = 0; nt < 4; ++nt) {
            f32x4 acch = {0.f, 0.f, 0.f, 0.f};
            f32x4 accd = {0.f, 0.f, 0.f, 0.f};
#pragma unroll
            for (int kb = 0; kb < 2; ++kb) {
                acch = __builtin_amdgcn_mfma_f32_16x16x32_bf16(ah[kb], bw[nt][kb], acch, 0, 0, 0);
                accd = __builtin_amdgcn_mfma_f32_16x16x32_bf16(ad[kb], bw[nt][kb], accd, 0, 0, 0);
            }
#pragma unroll
            for (int reg = 0; reg < 4; ++reg) {
                zh[reg] += tanhf(acch[reg] + b1v[nt]) * w2v[nt];
                zd[reg] += tanhf(accd[reg] + b1v[nt]) * w2v[nt];
            }
        }
        float s[4];
#pragma unroll
        for (int reg = 0; reg < 4; ++reg) {
#pragma unroll
            for (int off = 1; off < 16; off <<= 1) {
                zh[reg] += __shfl_xor(zh[reg], off, 64);
                zd[reg] += __shfl_xor(zd[reg], off, 64);
            }
            float mm = fmaxf(zh[reg], zd[reg]);
            float eh = expf(zh[reg] - mm), ed = expf(zd[reg] - mm);
            s[reg] = eh / (eh + ed);
        }
        int srcl = (m >> 2) * 16;
        float s0 = __shfl(s[0], srcl, 64), s1 = __shfl(s[1], srcl, 64);
        float s2 = __shfl(s[2], srcl, 64), s3 = __shfl(s[3], srcl, 64);
        int r3 = m & 3;
        float sv = (r3 == 0) ? s0 : (r3 == 1) ? s1 : (r3 == 2) ? s2 : s3;

        if (cf) {
            f32x4* cp = (f32x4*)(cf + base);
#pragma unroll
            for (int kb = 0; kb < 2; ++kb) {
                f32x4 v0, v1;
#pragma unroll
                for (int j = 0; j < 4; ++j) {
                    v0[j] = sv * hidf[kb][j]     + (1.f - sv) * dyf[kb][j];
                    v1[j] = sv * hidf[kb][4 + j] + (1.f - sv) * dyf[kb][4 + j];
                }
                cp[kb * 8 + quad * 2]     = v0;
                cp[kb * 8 + quad * 2 + 1] = v1;
                if (write_out && !f) {
#pragma unroll
                    for (int j = 0; j < 4; ++j) {
                        int k = kb * 32 + quad * 8 + j;
                        cb[base + k]     = __float2bfloat16(v0[j]);
                        cb[base + k + 4] = __float2bfloat16(v1[j]);
                    }
                }
            }
        } else {
#pragma unroll
            for (int kb = 0; kb < 2; ++kb)
#pragma unroll
                for (int j = 0; j < 8; ++j) {
                    int k = kb * 32 + quad * 8 + j;
                    float v = sv * hidf[kb][j] + (1.f - sv) * dyf[kb][j];
                    cb[base + k] = __float2bfloat16(v);
                }
        }
    }
}

// ---------------------------------------------------------------------------
extern "C" void kernel_launch(void* const* d_in, const int* in_sizes, int n_in,
                              void* d_out, int out_size, void* d_ws,
                              size_t ws_size, hipStream_t stream)
{
    const void* user_emb = d_in[0];
    const void* W_conv   = d_in[1];
    const void* b_conv   = d_in[2];
    const void* fus_w1   = d_in[3];
    const void* fus_b1   = d_in[4];
    const void* fus_w2   = d_in[5];
    const void* fus_b2   = d_in[6];
    const int* edge_nodes = (const int*)d_in[7];
    const int* edge_hyper = (const int*)d_in[8];

    const size_t ND = (size_t)N_USERS * DIM;   // 6,400,000

    // ws layout (fp32 word offsets) — proven base (51.83 MB):
    //   0        : flag
    //   16       : st fp32 [8448]
    //   8464     : head_e int [50000]
    //   58464    : head_n int [100000]
    //   158464   : next_e int [800000]
    //   958464   : next_n int [800000]
    //   1758464  : e bf16 [ED]
    //   3358464  : dy fp32 [ND]
    //   9758464  : h bf16 [ND]
    //   12958464 : optional fp32 carry [ND]  -> 77.43 MB
    float* ws = (float*)d_ws;
    int*   flag   = (int*)ws;
    float* st     = ws + 16;
    int*   head_e = (int*)(ws + 8464);
    int*   head_n = (int*)(ws + 58464);
    int*   next_e = (int*)(ws + 158464);
    int*   next_n = (int*)(ws + 958464);
    __hip_bfloat16* e_buf = (__hip_bfloat16*)(ws + 1758464);
    float* dy_buf = ws + 3358464;
    __hip_bfloat16* h = (__hip_bfloat16*)(ws + 9758464);
    float* carry_ws   = ws + 12958464;

    const size_t need_ws_carry = (12958464 + ND) * 4;
    const int use_ws = (ws_size >= need_ws_carry) ? 1 : 0;

    k_detect<<<1, 256, 0, stream>>>((const unsigned short*)user_emb, flag);
    k_convert_params<<<(8385 + 255) / 256, 256, 0, stream>>>(
        W_conv, b_conv, fus_w1, fus_b1, fus_w2, fus_b2, flag, st);
    k_transform<<<1024, 256, 0, stream>>>(user_emb, flag, st, h);

    for (int t = 0; t < T_STEPS; ++t) {
        const int* nodes = edge_nodes + (size_t)t * NNZ_E;
        const int* hyper = edge_hyper + (size_t)t * NNZ_E;
        int tag = t + 1;

        k_build<<<(NNZ_E + 255) / 256, 256, 0, stream>>>(
            nodes, hyper, head_e, next_e, head_n, next_n, tag);
        // E/8 chains per wave: 6250 waves -> 1563 blocks
        k_gather_e<<<1563, 256, 0, stream>>>(h, nodes, head_e, next_e, e_buf, tag);
        // N/8 chains per wave: 12500 waves -> 3125 blocks
        k_gather_n<<<3125, 256, 0, stream>>>(
            e_buf, hyper, head_n, next_n, dy_buf,
            d_out, carry_ws, flag, use_ws, (t == 0) ? 1 : 0, tag);

        if (t > 0) {
            k_fuse_mfma<<<1024, 256, 0, stream>>>(
                d_out, carry_ws, dy_buf, st, flag, use_ws,
                (t == T_STEPS - 1) ? 1 : 0);
        }
    }
}